// Round 5
// baseline (84.766 us; speedup 1.0000x reference)
//
#include <hip/hip_runtime.h>
#include <math.h>

#define HW   256
#define TR   32     // tile rows (owned)
#define TC   64     // tile cols (owned)
#define NBLK 2048   // 64 frames * 8 row-tiles * 4 col-tiles
#define BR   40     // hblur rows staged (TR + 2*4)
#define HC   68     // hblur/blur cols (TC + 2*2), multiple of 4
#define VR   36     // blur rows (TR + 2*2)
#define GR   34     // grad rows (TR + 2*1)
#define GC   66     // grad cols (TC + 2*1)
#define NHALO 196   // perimeter of GR x GC grid: 2*66 + 2*32
#define NG1  (BR * 17)  // 680 float4-groups in s_tmp
#define NG2  (VR * 17)  // 612 float4-groups in s_blur

namespace {
// Gaussian(5, std=1) computed in float64 then cast, matching _gaussian_1d
constexpr double kE2  = 0.13533528323661269189;  // exp(-2)
constexpr double kE05 = 0.60653065971263342360;  // exp(-0.5)
constexpr double kSum = 1.0 + 2.0 * kE2 + 2.0 * kE05;
constexpr float G0f = (float)(kE2 / kSum);
constexpr float G1f = (float)(kE05 / kSum);
constexpr float G2f = (float)(1.0 / kSum);
constexpr float T1  = 0.41421356237309503f;   // tan(22.5 deg)
constexpr float T2  = 2.41421356237309503f;   // tan(67.5 deg)
}

__global__ __launch_bounds__(256, 5)
void canny_tile_kernel(const float* __restrict__ imgA,
                       const float* __restrict__ imgB,
                       float* __restrict__ partials)
{
    __shared__ __align__(16) float s_tmp[BR * HC];   // horizontal gaussian
    __shared__ __align__(16) float s_blur[VR * HC];  // full blur (zero outside image)
    __shared__ float s_grad[GR * GC];                // channel-summed |grad|
    __shared__ float s_red[4];

    const int tid  = threadIdx.x;
    const int bid  = blockIdx.x;
    const int n    = bid >> 5;           // frame 0..63
    const int tile = bid & 31;
    const int ty0  = (tile >> 2) * TR;   // 8 row-tiles
    const int tx0  = (tile & 3) * TC;    // 4 col-tiles

    const int ox  = tid & 63;            // owned column within tile
    const int oy0 = (tid >> 6) * 8;      // owned rows oy0 .. oy0+7 (consecutive)

    // halo element (r,cc) for threads < NHALO (perimeter of GR x GC)
    int h_r = 0, h_cc = 0;
    if (tid < 66)        { h_r = 0;              h_cc = tid; }
    else if (tid < 132)  { h_r = GR - 1;         h_cc = tid - 66; }
    else if (tid < 164)  { h_r = tid - 132 + 1;  h_cc = 0; }
    else if (tid < NHALO){ h_r = tid - 164 + 1;  h_cc = GC - 1; }
    const bool has_halo = (tid < NHALO);
    const int  h_y = ty0 - 1 + h_r;
    const int  h_x = tx0 - 1 + h_cc;
    const bool h_in = ((unsigned)h_y < HW) && ((unsigned)h_x < HW);

    float e_first[8];
    float acc = 0.0f;

    for (int img = 0; img < 2; ++img) {
        const float* base = (img == 0 ? imgA : imgB) + (size_t)n * 3 * (HW * HW);
        float gxs[8], gys[8], gms[8];
        float hmag = 0.0f;
        #pragma unroll
        for (int k = 0; k < 8; ++k) { gxs[k] = 0.0f; gys[k] = 0.0f; gms[k] = 0.0f; }

        for (int c = 0; c < 3; ++c) {
            const float* plane = base + c * (HW * HW);

            // ---- A1: horizontal 5-tap gaussian, 4 outputs/group -> s_tmp[BR][HC]
            // s_tmp[r][cx] = hblur(y = ty0-4+r, x = tx0-2+cx); zero for y outside
            for (int g = tid; g < NG1; g += 256) {
                const int r  = g / 17;
                const int c4 = (g - r * 17) * 4;
                const int y  = ty0 - 4 + r;
                float4 o = make_float4(0.f, 0.f, 0.f, 0.f);
                if ((unsigned)y < HW) {
                    const int x0 = tx0 - 4 + c4;   // first tap of first output
                    const float* row = plane + y * HW;
                    if (x0 >= 0 && x0 <= HW - 8) {
                        const float4 a = *(const float4*)(row + x0);
                        const float4 b = *(const float4*)(row + x0 + 4);
                        o.x = G0f*a.x + G1f*a.y + G2f*a.z + G1f*a.w + G0f*b.x;
                        o.y = G0f*a.y + G1f*a.z + G2f*a.w + G1f*b.x + G0f*b.y;
                        o.z = G0f*a.z + G1f*a.w + G2f*b.x + G1f*b.y + G0f*b.z;
                        o.w = G0f*a.w + G1f*b.x + G2f*b.y + G1f*b.z + G0f*b.w;
                    } else {
                        float vv[8];
                        #pragma unroll
                        for (int j = 0; j < 8; ++j)
                            vv[j] = ((unsigned)(x0 + j) < HW) ? row[x0 + j] : 0.0f;
                        o.x = G0f*vv[0] + G1f*vv[1] + G2f*vv[2] + G1f*vv[3] + G0f*vv[4];
                        o.y = G0f*vv[1] + G1f*vv[2] + G2f*vv[3] + G1f*vv[4] + G0f*vv[5];
                        o.z = G0f*vv[2] + G1f*vv[3] + G2f*vv[4] + G1f*vv[5] + G0f*vv[6];
                        o.w = G0f*vv[3] + G1f*vv[4] + G2f*vv[5] + G1f*vv[6] + G0f*vv[7];
                    }
                }
                *(float4*)&s_tmp[r * HC + c4] = o;
            }
            __syncthreads();

            // ---- A2: vertical 5-tap gaussian, 4 outputs/group -> s_blur[VR][HC]
            // Sobel zero-pads BLUR, so blur outside the image must be exactly 0.
            for (int g = tid; g < NG2; g += 256) {
                const int r  = g / 17;
                const int c4 = (g - r * 17) * 4;
                const int y  = ty0 - 2 + r;
                float4 v = make_float4(0.f, 0.f, 0.f, 0.f);
                if ((unsigned)y < HW) {
                    const float4 t0 = *(const float4*)&s_tmp[(r    ) * HC + c4];
                    const float4 t1 = *(const float4*)&s_tmp[(r + 1) * HC + c4];
                    const float4 t2 = *(const float4*)&s_tmp[(r + 2) * HC + c4];
                    const float4 t3 = *(const float4*)&s_tmp[(r + 3) * HC + c4];
                    const float4 t4 = *(const float4*)&s_tmp[(r + 4) * HC + c4];
                    v.x = G0f*t0.x + G1f*t1.x + G2f*t2.x + G1f*t3.x + G0f*t4.x;
                    v.y = G0f*t0.y + G1f*t1.y + G2f*t2.y + G1f*t3.y + G0f*t4.y;
                    v.z = G0f*t0.z + G1f*t1.z + G2f*t2.z + G1f*t3.z + G0f*t4.z;
                    v.w = G0f*t0.w + G1f*t1.w + G2f*t2.w + G1f*t3.w + G0f*t4.w;
                    const int xb = tx0 - 2 + c4;
                    if (xb < 0 || xb > HW - 4) {   // only image-edge col groups
                        if ((unsigned)(xb + 0) >= HW) v.x = 0.f;
                        if ((unsigned)(xb + 1) >= HW) v.y = 0.f;
                        if ((unsigned)(xb + 2) >= HW) v.z = 0.f;
                        if ((unsigned)(xb + 3) >= HW) v.w = 0.f;
                    }
                }
                *(float4*)&s_blur[r * HC + c4] = v;
            }
            __syncthreads();

            // ---- A3a: interior sobel via row-sum factoring (8 consecutive rows)
            // owned pixel (oy,ox) = grad elem (oy+1, ox+1); center = blur(oy+2, ox+2)
            {
                float cd[10], rs[10];
                #pragma unroll
                for (int r = 0; r < 10; ++r) {
                    const float* b = &s_blur[(oy0 + 1 + r) * HC + (ox + 1)];
                    const float bl = b[0], bc = b[1], br = b[2];
                    cd[r] = bl - br;
                    rs[r] = bl + 2.0f * bc + br;
                }
                #pragma unroll
                for (int k = 0; k < 8; ++k) {
                    const float gx = cd[k] + 2.0f * cd[k + 1] + cd[k + 2];
                    const float gy = rs[k] - rs[k + 2];
                    gxs[k] += gx;
                    gys[k] += gy;
                    gms[k] += sqrtf(gx * gx + gy * gy);
                    s_grad[(oy0 + k + 1) * GC + (ox + 1)] = gms[k];
                }
            }

            // ---- A3b: halo sobel (perimeter of GR x GC), one elem per thread
            if (has_halo) {
                float gmag = 0.0f;
                if (h_in) {
                    const float* b = &s_blur[h_r * HC + h_cc];
                    const float b00 = b[0],        b01 = b[1],          b02 = b[2];
                    const float b10 = b[HC],                            b12 = b[HC + 2];
                    const float b20 = b[2 * HC],   b21 = b[2 * HC + 1], b22 = b[2 * HC + 2];
                    const float gx = (b00 + 2.0f * b10 + b20) - (b02 + 2.0f * b12 + b22);
                    const float gy = (b00 + 2.0f * b01 + b02) - (b20 + 2.0f * b21 + b22);
                    gmag = sqrtf(gx * gx + gy * gy);
                }
                hmag += gmag;
                s_grad[h_r * GC + h_cc] = hmag;
            }
            // no sync here: next A1 writes only s_tmp, whose readers (A2) are
            // already fenced by the post-A2 sync; A3 readers fenced below.
        }
        __syncthreads();  // s_grad complete for all channels

        // ---- Phase B: axis-based NMS + threshold at owned pixels
        // min(pos,neg) is symmetric in k -> k+4, so only the direction AXIS matters.
        #pragma unroll
        for (int k = 0; k < 8; ++k) {
            const int oy = oy0 + k;
            const float gc = gms[k];
            const float gx = gxs[k], gy = gys[k];
            const float ax = fabsf(gx), ay = fabsf(gy);
            int dy, dx;
            if (ay <= T1 * ax)      { dy = 0; dx = 1; }   // near 0/180 deg
            else if (ay >= T2 * ax) { dy = 1; dx = 0; }   // near +-90 deg
            else                    { dy = 1; dx = ((gx > 0.0f) == (gy > 0.0f)) ? 1 : -1; }
            const int ci = (oy + 1) * GC + (ox + 1);
            const float pos = gc - s_grad[ci + dy * GC + dx];
            const float neg = gc - s_grad[ci - dy * GC - dx];
            const float thin = (fminf(pos, neg) > 0.0f) ? gc : 0.0f;
            const float e    = (thin < 2.0f) ? 0.0f : thin;
            if (img == 0) e_first[k] = e;
            else          acc += fabsf(e - e_first[k]);
        }
        // no sync here: next img's A3 s_grad writes are fenced by two
        // intervening syncs (post-A1, post-A2) before they can occur.
    }

    // ---- deterministic block reduction
    #pragma unroll
    for (int off = 32; off > 0; off >>= 1) acc += __shfl_down(acc, off, 64);
    if ((tid & 63) == 0) s_red[tid >> 6] = acc;
    __syncthreads();
    if (tid == 0) partials[bid] = (s_red[0] + s_red[1]) + (s_red[2] + s_red[3]);
}

__global__ void final_reduce_kernel(const float* __restrict__ partials,
                                    float* __restrict__ out)
{
    __shared__ float s_red[4];
    const int tid = threadIdx.x;  // 256 threads
    float v = 0.0f;
    #pragma unroll
    for (int j = 0; j < 8; ++j) v += partials[tid + 256 * j];
    #pragma unroll
    for (int off = 32; off > 0; off >>= 1) v += __shfl_down(v, off, 64);
    if ((tid & 63) == 0) s_red[tid >> 6] = v;
    __syncthreads();
    if (tid == 0)
        out[0] = ((s_red[0] + s_red[1]) + (s_red[2] + s_red[3])) * (1.0f / 4194304.0f);
}

extern "C" void kernel_launch(void* const* d_in, const int* in_sizes, int n_in,
                              void* d_out, int out_size, void* d_ws, size_t ws_size,
                              hipStream_t stream)
{
    const float* tgt     = (const float*)d_in[0];  // data_input  [4,16,3,256,256]
    const float* out_img = (const float*)d_in[1];  // model_output
    float* partials = (float*)d_ws;                // 2048 floats

    canny_tile_kernel<<<NBLK, 256, 0, stream>>>(out_img, tgt, partials);
    final_reduce_kernel<<<1, 256, 0, stream>>>(partials, (float*)d_out);
}

// Round 6
// 64.747 us; speedup vs baseline: 1.3092x; 1.3092x over previous
//
#include <hip/hip_runtime.h>
#include <math.h>

#define HW   256
#define TR   16     // tile rows (owned)
#define TC   32     // tile cols (owned)
#define NBLK 8192   // 64 frames * 16 row-tiles * 8 col-tiles
#define BR   24     // hblur rows staged (TR + 2*4)
#define HC   36     // hblur/blur cols (TC + 2*2), multiple of 4
#define VR   20     // blur rows (TR + 2*2)
#define GR   18     // grad rows (TR + 2*1)
#define GC   34     // grad cols (TC + 2*1)
#define NHALO 100   // perimeter of GR x GC grid: 2*34 + 2*16
#define NG1  (BR * 9)   // 216 float4-groups in s_tmp  (<= 256: no loop)
#define NG2  (VR * 9)   // 180 float4-groups in s_blur (<= 256: no loop)

namespace {
// Gaussian(5, std=1) computed in float64 then cast, matching _gaussian_1d
constexpr double kE2  = 0.13533528323661269189;  // exp(-2)
constexpr double kE05 = 0.60653065971263342360;  // exp(-0.5)
constexpr double kSum = 1.0 + 2.0 * kE2 + 2.0 * kE05;
constexpr float G0f = (float)(kE2 / kSum);
constexpr float G1f = (float)(kE05 / kSum);
constexpr float G2f = (float)(1.0 / kSum);
constexpr float T1  = 0.41421356237309503f;   // tan(22.5 deg)
constexpr float T2  = 2.41421356237309503f;   // tan(67.5 deg)
__device__ __forceinline__ float fast_sqrtf(float x) {
    return __builtin_amdgcn_sqrtf(x);          // raw v_sqrt_f32 (1-2 ulp)
}
__device__ __forceinline__ int iclamp(int v, int lo, int hi) {
    return v < lo ? lo : (v > hi ? hi : v);
}
}

__global__ __launch_bounds__(256, 8)
void canny_tile_kernel(const float* __restrict__ imgA,
                       const float* __restrict__ imgB,
                       float* __restrict__ partials)
{
    __shared__ __align__(16) float s_tmp[BR * HC];   // horizontal gaussian
    __shared__ __align__(16) float s_blur[VR * HC];  // full blur (zero outside image)
    __shared__ float s_grad[GR * GC];                // channel-summed |grad|
    __shared__ float s_red[4];

    const int tid  = threadIdx.x;
    const int bid  = blockIdx.x;
    const int n    = bid >> 7;           // frame 0..63
    const int tile = bid & 127;
    const int ty0  = (tile >> 3) * TR;   // 16 row-tiles
    const int tx0  = (tile & 7) * TC;    // 8 col-tiles

    const int ox  = tid & 31;            // owned column within tile
    const int oy0 = (tid >> 5) * 2;      // owned rows oy0, oy0+1

    // ---- hoisted staging geometry (loop-invariant across img & channel) ----
    const int  q9  = tid / 9;            // group row
    const int  c4  = (tid - 9 * q9) * 4; // group start col (elements)
    const int  stw = q9 * HC + c4;       // s_tmp / s_blur write index (float4)
    // A1 (tid < NG1): hblur row y1, first tap x0
    const bool a1on = (tid < NG1);
    const int  y1   = ty0 - 4 + q9;
    const bool y1ok = ((unsigned)y1 < HW);
    const int  x0   = tx0 - 4 + c4;
    const int  ga   = y1 * HW + iclamp(x0, 0, HW - 4);       // aligned, clamped
    const int  gb   = y1 * HW + iclamp(x0 + 4, 0, HW - 4);
    // A2 (tid < NG2): vblur row y2, output cols xb2..xb2+3
    const bool a2on = (tid < NG2);
    const int  y2   = ty0 - 2 + q9;
    const bool y2ok = ((unsigned)y2 < HW);
    const int  xb2  = tx0 - 2 + c4;
    const bool ok0 = ((unsigned)(xb2 + 0) < HW), ok1 = ((unsigned)(xb2 + 1) < HW);
    const bool ok2 = ((unsigned)(xb2 + 2) < HW), ok3 = ((unsigned)(xb2 + 3) < HW);
    // A3a: sobel window base (blur rows oy0+1 .. oy0+4, cols ox+1..ox+3)
    const int  b3  = (oy0 + 1) * HC + (ox + 1);
    const int  gw  = (oy0 + 1) * GC + (ox + 1);   // s_grad write/read center, k=0
    // halo element (r,cc) for threads < NHALO (perimeter of GR x GC)
    int h_r = 0, h_cc = 0;
    if (tid < 34)        { h_r = 0;            h_cc = tid; }
    else if (tid < 68)   { h_r = GR - 1;       h_cc = tid - 34; }
    else if (tid < 84)   { h_r = tid - 68 + 1; h_cc = 0; }
    else if (tid < NHALO){ h_r = tid - 84 + 1; h_cc = GC - 1; }
    const bool has_halo = (tid < NHALO);
    const bool h_in = ((unsigned)(ty0 - 1 + h_r) < HW) && ((unsigned)(tx0 - 1 + h_cc) < HW);
    const int  h_b  = h_r * HC + h_cc;            // s_blur read base for halo sobel
    const int  h_gw = h_r * GC + h_cc;            // s_grad write

    float e_first[2];
    float acc = 0.0f;

    for (int img = 0; img < 2; ++img) {
        const float* base = (img == 0 ? imgA : imgB) + (size_t)n * 3 * (HW * HW);
        float gxs[2], gys[2], gms[2];
        float hmag = 0.0f;
        #pragma unroll
        for (int k = 0; k < 2; ++k) { gxs[k] = 0.0f; gys[k] = 0.0f; gms[k] = 0.0f; }

        for (int c = 0; c < 3; ++c) {
            const float* plane = base + c * (HW * HW);

            // ---- A1: horizontal 5-tap gaussian, 4 outputs/thread -> s_tmp
            if (a1on) {
                float4 o = make_float4(0.f, 0.f, 0.f, 0.f);
                if (y1ok) {
                    const float4 a = *(const float4*)(plane + ga);
                    const float4 b = *(const float4*)(plane + gb);
                    o.x = G0f*a.x + G1f*a.y + G2f*a.z + G1f*a.w + G0f*b.x;
                    o.y = G0f*a.y + G1f*a.z + G2f*a.w + G1f*b.x + G0f*b.y;
                    o.z = G0f*a.z + G1f*a.w + G2f*b.x + G1f*b.y + G0f*b.z;
                    o.w = G0f*a.w + G1f*b.x + G2f*b.y + G1f*b.z + G0f*b.w;
                    if (x0 < 0) {                 // left image edge (x0 == -4; a = row[0..3])
                        o.x = G0f*a.x;
                        o.y = G1f*a.x + G0f*a.y;
                        o.z = G2f*a.x + G1f*a.y + G0f*a.z;
                        o.w = G1f*a.x + G2f*a.y + G1f*a.z + G0f*a.w;
                    } else if (x0 > HW - 8) {     // right image edge (x0 == 252; a = row[252..255])
                        o.x = G0f*a.x + G1f*a.y + G2f*a.z + G1f*a.w;
                        o.y = G0f*a.y + G1f*a.z + G2f*a.w;
                        o.z = G0f*a.z + G1f*a.w;
                        o.w = G0f*a.w;
                    }
                }
                *(float4*)&s_tmp[stw] = o;
            }
            __syncthreads();

            // ---- A2: vertical 5-tap gaussian, 4 outputs/thread -> s_blur
            // Sobel zero-pads BLUR, so blur outside the image must be exactly 0.
            if (a2on) {
                float4 v = make_float4(0.f, 0.f, 0.f, 0.f);
                if (y2ok) {
                    const float4 t0 = *(const float4*)&s_tmp[stw];
                    const float4 t1 = *(const float4*)&s_tmp[stw + 1 * HC];
                    const float4 t2 = *(const float4*)&s_tmp[stw + 2 * HC];
                    const float4 t3 = *(const float4*)&s_tmp[stw + 3 * HC];
                    const float4 t4 = *(const float4*)&s_tmp[stw + 4 * HC];
                    v.x = ok0 ? (G0f*t0.x + G1f*t1.x + G2f*t2.x + G1f*t3.x + G0f*t4.x) : 0.f;
                    v.y = ok1 ? (G0f*t0.y + G1f*t1.y + G2f*t2.y + G1f*t3.y + G0f*t4.y) : 0.f;
                    v.z = ok2 ? (G0f*t0.z + G1f*t1.z + G2f*t2.z + G1f*t3.z + G0f*t4.z) : 0.f;
                    v.w = ok3 ? (G0f*t0.w + G1f*t1.w + G2f*t2.w + G1f*t3.w + G0f*t4.w) : 0.f;
                }
                *(float4*)&s_blur[stw] = v;
            }
            __syncthreads();

            // ---- A3a: interior sobel via row-sum factoring (2 consecutive rows)
            // owned pixel (oy,ox) = grad elem (oy+1, ox+1); center = blur(oy+2, ox+2)
            {
                float cd[4], rs[4];
                #pragma unroll
                for (int r = 0; r < 4; ++r) {
                    const float* b = &s_blur[b3 + r * HC];
                    const float bl = b[0], bc = b[1], br = b[2];
                    cd[r] = bl - br;
                    rs[r] = bl + 2.0f * bc + br;
                }
                #pragma unroll
                for (int k = 0; k < 2; ++k) {
                    const float gx = cd[k] + 2.0f * cd[k + 1] + cd[k + 2];
                    const float gy = rs[k] - rs[k + 2];
                    gxs[k] += gx;
                    gys[k] += gy;
                    gms[k] += fast_sqrtf(gx * gx + gy * gy);
                    s_grad[gw + k * GC] = gms[k];
                }
            }

            // ---- A3b: halo sobel (perimeter of GR x GC), one elem per thread
            if (has_halo) {
                float gmag = 0.0f;
                if (h_in) {
                    const float* b = &s_blur[h_b];
                    const float b00 = b[0],        b01 = b[1],          b02 = b[2];
                    const float b10 = b[HC],                            b12 = b[HC + 2];
                    const float b20 = b[2 * HC],   b21 = b[2 * HC + 1], b22 = b[2 * HC + 2];
                    const float gx = (b00 + 2.0f * b10 + b20) - (b02 + 2.0f * b12 + b22);
                    const float gy = (b00 + 2.0f * b01 + b02) - (b20 + 2.0f * b21 + b22);
                    gmag = fast_sqrtf(gx * gx + gy * gy);
                }
                hmag += gmag;
                s_grad[h_gw] = hmag;
            }
            // no sync here: next A1 writes only s_tmp, whose readers (A2) are
            // fenced by the post-A2 sync; s_blur readers (A3) complete before
            // any thread passes the next post-A1 sync.
        }
        __syncthreads();  // s_grad complete for all channels

        // ---- Phase B: axis-based NMS + threshold at owned pixels
        // min(pos,neg) is symmetric in k -> k+4, so only the direction AXIS matters.
        #pragma unroll
        for (int k = 0; k < 2; ++k) {
            const float gc = gms[k];
            const float gx = gxs[k], gy = gys[k];
            const float ax = fabsf(gx), ay = fabsf(gy);
            int dy, dx;
            if (ay <= T1 * ax)      { dy = 0; dx = 1; }   // near 0/180 deg
            else if (ay >= T2 * ax) { dy = 1; dx = 0; }   // near +-90 deg
            else                    { dy = 1; dx = ((gx > 0.0f) == (gy > 0.0f)) ? 1 : -1; }
            const int ci = gw + k * GC;
            const float pos = gc - s_grad[ci + dy * GC + dx];
            const float neg = gc - s_grad[ci - dy * GC - dx];
            const float thin = (fminf(pos, neg) > 0.0f) ? gc : 0.0f;
            const float e    = (thin < 2.0f) ? 0.0f : thin;
            if (img == 0) e_first[k] = e;
            else          acc += fabsf(e - e_first[k]);
        }
        // no sync here: next img's A3 s_grad writes are fenced by two
        // intervening syncs (post-A1, post-A2) before they can occur.
    }

    // ---- deterministic block reduction
    #pragma unroll
    for (int off = 32; off > 0; off >>= 1) acc += __shfl_down(acc, off, 64);
    if ((tid & 63) == 0) s_red[tid >> 6] = acc;
    __syncthreads();
    if (tid == 0) partials[bid] = (s_red[0] + s_red[1]) + (s_red[2] + s_red[3]);
}

__global__ void final_reduce_kernel(const float* __restrict__ partials,
                                    float* __restrict__ out)
{
    __shared__ float s_red[4];
    const int tid = threadIdx.x;  // 256 threads
    float v = 0.0f;
    #pragma unroll
    for (int j = 0; j < 32; ++j) v += partials[tid + 256 * j];
    #pragma unroll
    for (int off = 32; off > 0; off >>= 1) v += __shfl_down(v, off, 64);
    if ((tid & 63) == 0) s_red[tid >> 6] = v;
    __syncthreads();
    if (tid == 0)
        out[0] = ((s_red[0] + s_red[1]) + (s_red[2] + s_red[3])) * (1.0f / 4194304.0f);
}

extern "C" void kernel_launch(void* const* d_in, const int* in_sizes, int n_in,
                              void* d_out, int out_size, void* d_ws, size_t ws_size,
                              hipStream_t stream)
{
    const float* tgt     = (const float*)d_in[0];  // data_input  [4,16,3,256,256]
    const float* out_img = (const float*)d_in[1];  // model_output
    float* partials = (float*)d_ws;                // 8192 floats

    canny_tile_kernel<<<NBLK, 256, 0, stream>>>(out_img, tgt, partials);
    final_reduce_kernel<<<1, 256, 0, stream>>>(partials, (float*)d_out);
}